// Round 4
// baseline (228.725 us; speedup 1.0000x reference)
//
#include <hip/hip_runtime.h>
#include <math.h>

// Problem constants
#define CC 384
#define DD 768
#define TT 32
#define NN 196
#define BB 16
#define KK 16
#define NSAMP 500
#define JV 18816          // N*C/4 (float4 groups per frame)
#define FRAME 75264       // N*C

__device__ __forceinline__ float gelu_exact(float x) {
    return 0.5f * x * (1.0f + erff(x * 0.70710678118654752440f));
}

// ---------------- Kernel 1: mean+max pool over N, fused LayerNorm ----------------
// grid = B*T blocks, block = (96,4). Writes xbar[row][0:768] already LayerNorm'd.
__global__ __launch_bounds__(384) void pool_kernel(const float* __restrict__ x,
                                                   const float* __restrict__ ln_g,
                                                   const float* __restrict__ ln_b,
                                                   float* __restrict__ xbar) {
    int row = blockIdx.x;                       // b*T + t
    const float4* xp = (const float4*)(x + (size_t)row * NN * CC);
    int tx = threadIdx.x;                       // 0..95 channel float4 group
    int ty = threadIdx.y;                       // 0..3
    float4 s = make_float4(0.f, 0.f, 0.f, 0.f);
    float4 m = make_float4(-INFINITY, -INFINITY, -INFINITY, -INFINITY);
    for (int n = ty; n < NN; n += 4) {
        float4 v = xp[n * 96 + tx];
        s.x += v.x; s.y += v.y; s.z += v.z; s.w += v.w;
        m.x = fmaxf(m.x, v.x); m.y = fmaxf(m.y, v.y);
        m.z = fmaxf(m.z, v.z); m.w = fmaxf(m.w, v.w);
    }
    __shared__ float4 ssum[4][96];
    __shared__ float4 smax[4][96];
    __shared__ float xf[DD];
    ssum[ty][tx] = s;
    smax[ty][tx] = m;
    __syncthreads();
    if (ty == 0) {
        for (int r = 1; r < 4; ++r) {
            float4 a = ssum[r][tx];
            s.x += a.x; s.y += a.y; s.z += a.z; s.w += a.w;
            float4 b = smax[r][tx];
            m.x = fmaxf(m.x, b.x); m.y = fmaxf(m.y, b.y);
            m.z = fmaxf(m.z, b.z); m.w = fmaxf(m.w, b.w);
        }
        const float invn = 1.0f / (float)NN;
        xf[4*tx+0] = s.x * invn; xf[4*tx+1] = s.y * invn;
        xf[4*tx+2] = s.z * invn; xf[4*tx+3] = s.w * invn;
        xf[CC + 4*tx+0] = m.x; xf[CC + 4*tx+1] = m.y;
        xf[CC + 4*tx+2] = m.z; xf[CC + 4*tx+3] = m.w;
    }
    __syncthreads();
    int tid = ty * 96 + tx;                     // 0..383
    float e0 = xf[tid], e1 = xf[tid + CC];
    float ps = e0 + e1, pq = e0 * e0 + e1 * e1;
    #pragma unroll
    for (int off = 32; off; off >>= 1) {
        ps += __shfl_down(ps, off);
        pq += __shfl_down(pq, off);
    }
    __shared__ float red[12];
    __shared__ float mv[2];
    int wv = tid >> 6;
    if ((tid & 63) == 0) { red[wv] = ps; red[6 + wv] = pq; }
    __syncthreads();
    if (tid == 0) {
        float su = 0.f, sq = 0.f;
        #pragma unroll
        for (int i = 0; i < 6; ++i) { su += red[i]; sq += red[6 + i]; }
        float mean = su * (1.0f / DD);
        float var  = sq * (1.0f / DD) - mean * mean;
        mv[0] = mean;
        mv[1] = rsqrtf(var + 1e-5f);
    }
    __syncthreads();
    float mean = mv[0], inv = mv[1];
    float* o = xbar + (size_t)row * DD;
    o[tid]      = (e0 - mean) * inv * ln_g[tid]      + ln_b[tid];
    o[tid + CC] = (e1 - mean) * inv * ln_g[tid + CC] + ln_b[tid + CC];
}

// ---------------- Kernel 2: FC_in (768->768) + bias + GELU, x via scalar loads ----------------
// grid = (128 rowg, 3 colg), 256 threads. 4 rows x 256 cols, full K=768.
__global__ __launch_bounds__(256) void fcin_kernel(const float* __restrict__ xbar,
                                                   const float* __restrict__ w_in,
                                                   const float* __restrict__ b_in,
                                                   float* __restrict__ h1) {
    int tid = threadIdx.x;
    int row0 = blockIdx.x * 4;
    int col  = blockIdx.y * 256 + tid;
    const float* xr = xbar + (size_t)row0 * DD;   // wave-uniform -> scalar loads
    const float* wp = w_in + col;
    float a0 = b_in[col], a1 = a0, a2 = a0, a3 = a0;
    #pragma unroll 4
    for (int i = 0; i < DD; ++i) {
        float wv = wp[(size_t)i * DD];
        a0 += xr[i]          * wv;
        a1 += xr[DD + i]     * wv;
        a2 += xr[2 * DD + i] * wv;
        a3 += xr[3 * DD + i] * wv;
    }
    h1[(size_t)(row0 + 0) * DD + col] = gelu_exact(a0);
    h1[(size_t)(row0 + 1) * DD + col] = gelu_exact(a1);
    h1[(size_t)(row0 + 2) * DD + col] = gelu_exact(a2);
    h1[(size_t)(row0 + 3) * DD + col] = gelu_exact(a3);
}

// ---------------- Kernel 3: mlp1 = gelu([h1_local | mean_T(h1_global)] @ w1 + b1) ----------------
// grid = (128 rowg, 2 colg), 192 threads. Global pool recomputed per block (cheap, L2).
__global__ __launch_bounds__(192) void mlp1_kernel(const float* __restrict__ h1,
                                                   const float* __restrict__ w1,
                                                   const float* __restrict__ b1,
                                                   float* __restrict__ h2) {
    __shared__ float gs[CC];
    int tid = threadIdx.x;
    int row0 = blockIdx.x * 4;
    int b = row0 >> 5;
    int col = blockIdx.y * 192 + tid;

    // Phase A: gs[i] = mean over T of h1[b, t, CC+i]  (coalesced: lanes over i)
    const float* hb = h1 + (size_t)b * TT * DD + CC;
    for (int i = tid; i < CC; i += 192) {
        float s = 0.f;
        #pragma unroll 8
        for (int t = 0; t < TT; ++t) s += hb[(size_t)t * DD + i];
        gs[i] = s * (1.0f / TT);
    }
    __syncthreads();

    // Phase B: GEMM. Local half: per-row scalar x loads; global half: shared gs.
    const float* xr = h1 + (size_t)row0 * DD;     // wave-uniform -> scalar loads
    const float* wp = w1 + col;
    float a0 = b1[col], a1 = a0, a2 = a0, a3 = a0;
    #pragma unroll 4
    for (int i = 0; i < CC; ++i) {
        float wv = wp[(size_t)i * CC];
        a0 += xr[i]          * wv;
        a1 += xr[DD + i]     * wv;
        a2 += xr[2 * DD + i] * wv;
        a3 += xr[3 * DD + i] * wv;
    }
    float ag = 0.f;
    #pragma unroll 4
    for (int i = 0; i < CC; ++i)
        ag += gs[i] * wp[(size_t)(CC + i) * CC];
    a0 += ag; a1 += ag; a2 += ag; a3 += ag;

    h2[(size_t)(row0 + 0) * CC + col] = gelu_exact(a0);
    h2[(size_t)(row0 + 1) * CC + col] = gelu_exact(a1);
    h2[(size_t)(row0 + 2) * CC + col] = gelu_exact(a2);
    h2[(size_t)(row0 + 3) * CC + col] = gelu_exact(a3);
}

// ---------------- Kernel 4: mlp2 (384->192, GELU, x w3, reduce) -> scores ----------------
// grid = 512 (one row per block), 192 threads.
__global__ __launch_bounds__(192) void mlp2_kernel(const float* __restrict__ h2,
                                                   const float* __restrict__ w2,
                                                   const float* __restrict__ b2,
                                                   const float* __restrict__ w3,
                                                   const float* __restrict__ b3,
                                                   float* __restrict__ scores) {
    int row = blockIdx.x, tid = threadIdx.x;
    const float* hr = h2 + (size_t)row * CC;      // wave-uniform -> scalar loads
    const float* wp = w2 + tid;
    float a = b2[tid];
    #pragma unroll 4
    for (int i = 0; i < CC; ++i)
        a += hr[i] * wp[(size_t)i * 192];
    float v = gelu_exact(a) * w3[tid];
    #pragma unroll
    for (int off = 32; off; off >>= 1) v += __shfl_down(v, off);
    __shared__ float red[3];
    if ((tid & 63) == 0) red[tid >> 6] = v;
    __syncthreads();
    if (tid == 0) scores[row] = red[0] + red[1] + red[2] + b3[0];
}

// ---------------- Kernel 5: min-max norm + perturbed top-k -> indicators ----------------
__global__ __launch_bounds__(512) void topk_kernel(const float* __restrict__ scores,
                                                   const float* __restrict__ noise,
                                                   float* __restrict__ ind) {
    __shared__ float ns[TT];
    __shared__ float mnmx[2];
    __shared__ int counts[KK * TT];
    int b = blockIdx.x, tid = threadIdx.x;

    if (tid < TT) ns[tid] = scores[b * TT + tid];
    counts[tid & 511] = 0;
    __syncthreads();
    if (tid == 0) {
        float mn = ns[0], mx = ns[0];
        for (int t = 1; t < TT; ++t) { mn = fminf(mn, ns[t]); mx = fmaxf(mx, ns[t]); }
        mnmx[0] = mn; mnmx[1] = mx;
    }
    __syncthreads();
    if (tid < TT) ns[tid] = (ns[tid] - mnmx[0]) / (mnmx[1] - mnmx[0] + 1e-5f);
    __syncthreads();

    if (tid < NSAMP) {
        const float* nb = noise + ((size_t)b * NSAMP + tid) * TT;
        float p[TT];
        #pragma unroll
        for (int t = 0; t < TT; ++t) p[t] = ns[t] + nb[t] * 0.05f;
        int k = 0;
        #pragma unroll
        for (int t = 0; t < TT; ++t) {
            int rank = 0;
            #pragma unroll
            for (int u = 0; u < TT; ++u)
                rank += (p[u] > p[t] || (p[u] == p[t] && u < t)) ? 1 : 0;
            if (rank < KK) { atomicAdd(&counts[k * TT + t], 1); ++k; }
        }
    }
    __syncthreads();
    ind[b * (KK * TT) + tid] = (float)counts[tid] * (1.0f / NSAMP);
}

// ---------------- Kernel 6: weighted gather with active-frame compaction ----------------
__global__ __launch_bounds__(256) void gather_kernel(const float* __restrict__ x,
                                                     const float* __restrict__ ind,
                                                     float* __restrict__ out) {
    __shared__ float w[KK * TT];
    __shared__ int act[TT];
    __shared__ int nact_s;
    int b = blockIdx.y;
    int tid = threadIdx.x;
    w[tid] = ind[b * (KK * TT) + tid];
    w[256 + tid] = ind[b * (KK * TT) + 256 + tid];
    __syncthreads();
    if (tid == 0) {
        int n = 0;
        for (int t = 0; t < TT; ++t) {
            float s = 0.f;
            #pragma unroll
            for (int k = 0; k < KK; ++k) s += fabsf(w[k * TT + t]);
            if (s != 0.f) act[n++] = t;
        }
        nact_s = n;
    }
    __syncthreads();
    int nact = nact_s;

    int j4 = blockIdx.x * 256 + tid;
    if (j4 >= JV) return;

    const float4* xb = (const float4*)(x + (size_t)b * TT * FRAME);
    float4 acc[KK];
    #pragma unroll
    for (int k = 0; k < KK; ++k) acc[k] = make_float4(0.f, 0.f, 0.f, 0.f);

    for (int it = 0; it < nact; ++it) {
        int t = act[it];
        float4 v = xb[(size_t)t * JV + j4];
        #pragma unroll
        for (int k = 0; k < KK; ++k) {
            float wk = w[k * TT + t];
            acc[k].x += wk * v.x; acc[k].y += wk * v.y;
            acc[k].z += wk * v.z; acc[k].w += wk * v.w;
        }
    }
    float4* ob = (float4*)(out + (size_t)b * KK * FRAME);
    #pragma unroll
    for (int k = 0; k < KK; ++k)
        ob[(size_t)k * JV + j4] = acc[k];
}

extern "C" void kernel_launch(void* const* d_in, const int* in_sizes, int n_in,
                              void* d_out, int out_size, void* d_ws, size_t ws_size,
                              hipStream_t stream) {
    const float* x     = (const float*)d_in[0];
    const float* noise = (const float*)d_in[1];
    const float* ln_g  = (const float*)d_in[2];
    const float* ln_b  = (const float*)d_in[3];
    const float* w_in  = (const float*)d_in[4];
    const float* b_in  = (const float*)d_in[5];
    const float* w1    = (const float*)d_in[6];
    const float* b1    = (const float*)d_in[7];
    const float* w2    = (const float*)d_in[8];
    const float* b2    = (const float*)d_in[9];
    const float* w3    = (const float*)d_in[10];
    const float* b3    = (const float*)d_in[11];
    float* out = (float*)d_out;

    float* ws     = (float*)d_ws;
    float* xbar   = ws;                       // 512*768 (LayerNorm'd)
    float* h1     = xbar + 512 * DD;          // 512*768
    float* h2     = h1 + 512 * DD;            // 512*384
    float* scores = h2 + 512 * CC;            // 512
    float* ind    = scores + 512;             // 16*512

    hipLaunchKernelGGL(pool_kernel, dim3(BB * TT), dim3(96, 4), 0, stream,
                       x, ln_g, ln_b, xbar);
    hipLaunchKernelGGL(fcin_kernel, dim3(128, 3), dim3(256), 0, stream,
                       xbar, w_in, b_in, h1);
    hipLaunchKernelGGL(mlp1_kernel, dim3(128, 2), dim3(192), 0, stream,
                       h1, w1, b1, h2);
    hipLaunchKernelGGL(mlp2_kernel, dim3(512), dim3(192), 0, stream,
                       h2, w2, b2, w3, b3, scores);
    hipLaunchKernelGGL(topk_kernel, dim3(BB), dim3(512), 0, stream, scores, noise, ind);
    hipLaunchKernelGGL(gather_kernel, dim3((JV + 255) / 256, BB), dim3(256), 0, stream,
                       x, ind, out);
}

// Round 5
// 135.654 us; speedup vs baseline: 1.6861x; 1.6861x over previous
//
#include <hip/hip_runtime.h>
#include <math.h>

// Problem constants
#define CC 384
#define DD 768
#define TT 32
#define NN 196
#define BB 16
#define KK 16
#define NSAMP 500
#define JV 18816          // N*C/4 (float4 groups per frame)
#define FRAME 75264       // N*C

__device__ __forceinline__ float gelu_exact(float x) {
    return 0.5f * x * (1.0f + erff(x * 0.70710678118654752440f));
}

// ---------------- Kernel 1: mean+max pool over N, fused LayerNorm ----------------
__global__ __launch_bounds__(384) void pool_kernel(const float* __restrict__ x,
                                                   const float* __restrict__ ln_g,
                                                   const float* __restrict__ ln_b,
                                                   float* __restrict__ xbar) {
    int row = blockIdx.x;                       // b*T + t
    const float4* xp = (const float4*)(x + (size_t)row * NN * CC);
    int tx = threadIdx.x;                       // 0..95
    int ty = threadIdx.y;                       // 0..3
    float4 s = make_float4(0.f, 0.f, 0.f, 0.f);
    float4 m = make_float4(-INFINITY, -INFINITY, -INFINITY, -INFINITY);
    for (int n = ty; n < NN; n += 4) {
        float4 v = xp[n * 96 + tx];
        s.x += v.x; s.y += v.y; s.z += v.z; s.w += v.w;
        m.x = fmaxf(m.x, v.x); m.y = fmaxf(m.y, v.y);
        m.z = fmaxf(m.z, v.z); m.w = fmaxf(m.w, v.w);
    }
    __shared__ float4 ssum[4][96];
    __shared__ float4 smax[4][96];
    __shared__ float xf[DD];
    ssum[ty][tx] = s;
    smax[ty][tx] = m;
    __syncthreads();
    if (ty == 0) {
        for (int r = 1; r < 4; ++r) {
            float4 a = ssum[r][tx];
            s.x += a.x; s.y += a.y; s.z += a.z; s.w += a.w;
            float4 b = smax[r][tx];
            m.x = fmaxf(m.x, b.x); m.y = fmaxf(m.y, b.y);
            m.z = fmaxf(m.z, b.z); m.w = fmaxf(m.w, b.w);
        }
        const float invn = 1.0f / (float)NN;
        xf[4*tx+0] = s.x * invn; xf[4*tx+1] = s.y * invn;
        xf[4*tx+2] = s.z * invn; xf[4*tx+3] = s.w * invn;
        xf[CC + 4*tx+0] = m.x; xf[CC + 4*tx+1] = m.y;
        xf[CC + 4*tx+2] = m.z; xf[CC + 4*tx+3] = m.w;
    }
    __syncthreads();
    int tid = ty * 96 + tx;                     // 0..383
    float e0 = xf[tid], e1 = xf[tid + CC];
    float ps = e0 + e1, pq = e0 * e0 + e1 * e1;
    #pragma unroll
    for (int off = 32; off; off >>= 1) {
        ps += __shfl_down(ps, off);
        pq += __shfl_down(pq, off);
    }
    __shared__ float red[12];
    __shared__ float mv[2];
    int wv = tid >> 6;
    if ((tid & 63) == 0) { red[wv] = ps; red[6 + wv] = pq; }
    __syncthreads();
    if (tid == 0) {
        float su = 0.f, sq = 0.f;
        #pragma unroll
        for (int i = 0; i < 6; ++i) { su += red[i]; sq += red[6 + i]; }
        float mean = su * (1.0f / DD);
        float var  = sq * (1.0f / DD) - mean * mean;
        mv[0] = mean;
        mv[1] = rsqrtf(var + 1e-5f);
    }
    __syncthreads();
    float mean = mv[0], inv = mv[1];
    float* o = xbar + (size_t)row * DD;
    o[tid]      = (e0 - mean) * inv * ln_g[tid]      + ln_b[tid];
    o[tid + CC] = (e1 - mean) * inv * ln_g[tid + CC] + ln_b[tid + CC];
}

// ---------------- Kernel 2a: FC_in partial GEMM, split-K=8 ----------------
// grid (64 rowg[8], 3 colg[256], 8 kc[96]), 256 threads. 24 waves/CU.
__global__ __launch_bounds__(256) void fcinA_kernel(const float* __restrict__ xbar,
                                                    const float* __restrict__ w_in,
                                                    float* __restrict__ pfc) {
    __shared__ float xs[8][96];
    int tid = threadIdx.x;
    int row0 = blockIdx.x * 8;
    int col  = blockIdx.y * 256 + tid;
    int k0   = blockIdx.z * 96;
    if (tid < 192) {                       // stage 8 rows x 96 = 192 float4
        int r = tid / 24, j = tid % 24;
        ((float4*)xs[r])[j] = *(const float4*)(xbar + (size_t)(row0 + r) * DD + k0 + 4 * j);
    }
    __syncthreads();

    float acc[8] = {0.f, 0.f, 0.f, 0.f, 0.f, 0.f, 0.f, 0.f};
    const float* wp = w_in + (size_t)k0 * DD + col;
    #pragma unroll 2
    for (int i = 0; i < 96; i += 4) {
        float w0 = wp[(size_t)(i + 0) * DD];
        float w1 = wp[(size_t)(i + 1) * DD];
        float w2 = wp[(size_t)(i + 2) * DD];
        float w3 = wp[(size_t)(i + 3) * DD];
        #pragma unroll
        for (int r = 0; r < 8; ++r) {
            float4 xv = *(const float4*)&xs[r][i];
            acc[r] += xv.x * w0 + xv.y * w1 + xv.z * w2 + xv.w * w3;
        }
    }
    float* o = pfc + ((size_t)blockIdx.z * 512 + row0) * DD + col;
    #pragma unroll
    for (int r = 0; r < 8; ++r) o[(size_t)r * DD] = acc[r];
}

// ---------------- Kernel 2b: combine 8 partials + bias + GELU -> h1 ----------------
// grid 384, 256 threads; one float4 per thread over 512x768.
__global__ __launch_bounds__(256) void fcinB_kernel(const float* __restrict__ pfc,
                                                    const float* __restrict__ b_in,
                                                    float* __restrict__ h1) {
    int gid = blockIdx.x * 256 + threadIdx.x;   // 0..98303
    int row = gid / 192, c4 = gid % 192;
    const float4* p4 = (const float4*)pfc;
    float4 s = ((const float4*)b_in)[c4];
    #pragma unroll
    for (int kc = 0; kc < 8; ++kc) {
        float4 v = p4[((size_t)kc * 512 + row) * 192 + c4];
        s.x += v.x; s.y += v.y; s.z += v.z; s.w += v.w;
    }
    float4 r;
    r.x = gelu_exact(s.x); r.y = gelu_exact(s.y);
    r.z = gelu_exact(s.z); r.w = gelu_exact(s.w);
    ((float4*)h1)[(size_t)row * 192 + c4] = r;
}

// ---------------- Kernel 2c: global pool + global-half GEMM -> G[b][col] ----------------
// grid (16 b, 3 colg[128]), 128 threads.
__global__ __launch_bounds__(128) void gpoolG_kernel(const float* __restrict__ h1,
                                                     const float* __restrict__ w1,
                                                     float* __restrict__ G) {
    __shared__ float gs[CC];
    int tid = threadIdx.x;
    int b = blockIdx.x;
    const float* hb = h1 + (size_t)b * TT * DD + CC;
    for (int i = tid; i < CC; i += 128) {
        float s = 0.f;
        #pragma unroll 8
        for (int t = 0; t < TT; ++t) s += hb[(size_t)t * DD + i];
        gs[i] = s * (1.0f / TT);
    }
    __syncthreads();
    int col = blockIdx.y * 128 + tid;
    float acc = 0.f;
    const float* wp = w1 + (size_t)CC * CC + col;   // rows 384.. of w1
    #pragma unroll 16
    for (int i = 0; i < CC; ++i)
        acc += gs[i] * wp[(size_t)i * CC];
    G[b * CC + col] = acc;
}

// ---------------- Kernel 2d: mlp1 local-half partial GEMM, split-K=4 ----------------
// grid (128 rowg[4], 2 colg[192], 4 kc[96]), 192 threads.
__global__ __launch_bounds__(192) void mlp1A_kernel(const float* __restrict__ h1,
                                                    const float* __restrict__ w1,
                                                    float* __restrict__ pm1) {
    __shared__ float xs[4][96];
    int tid = threadIdx.x;
    int row0 = blockIdx.x * 4;
    int col  = blockIdx.y * 192 + tid;
    int k0   = blockIdx.z * 96;
    if (tid < 96) {                        // 4 rows x 24 float4
        int r = tid / 24, j = tid % 24;
        ((float4*)xs[r])[j] = *(const float4*)(h1 + (size_t)(row0 + r) * DD + k0 + 4 * j);
    }
    __syncthreads();

    float acc[4] = {0.f, 0.f, 0.f, 0.f};
    const float* wp = w1 + (size_t)k0 * CC + col;
    #pragma unroll 2
    for (int i = 0; i < 96; i += 4) {
        float w0 = wp[(size_t)(i + 0) * CC];
        float w1v = wp[(size_t)(i + 1) * CC];
        float w2 = wp[(size_t)(i + 2) * CC];
        float w3 = wp[(size_t)(i + 3) * CC];
        #pragma unroll
        for (int r = 0; r < 4; ++r) {
            float4 xv = *(const float4*)&xs[r][i];
            acc[r] += xv.x * w0 + xv.y * w1v + xv.z * w2 + xv.w * w3;
        }
    }
    float* o = pm1 + ((size_t)blockIdx.z * 512 + row0) * CC + col;
    #pragma unroll
    for (int r = 0; r < 4; ++r) o[(size_t)r * CC] = acc[r];
}

// ---------------- Kernel 2e: combine 4 partials + G + bias + GELU -> h2 ----------------
// grid 192, 256 threads; one float4 per thread over 512x384.
__global__ __launch_bounds__(256) void mlp1B_kernel(const float* __restrict__ pm1,
                                                    const float* __restrict__ G,
                                                    const float* __restrict__ b1,
                                                    float* __restrict__ h2) {
    int gid = blockIdx.x * 256 + threadIdx.x;   // 0..49151
    int row = gid / 96, c4 = gid % 96;
    int b = row >> 5;
    const float4* p4 = (const float4*)pm1;
    float4 s = ((const float4*)b1)[c4];
    float4 gv = ((const float4*)G)[b * 96 + c4];
    s.x += gv.x; s.y += gv.y; s.z += gv.z; s.w += gv.w;
    #pragma unroll
    for (int kc = 0; kc < 4; ++kc) {
        float4 v = p4[((size_t)kc * 512 + row) * 96 + c4];
        s.x += v.x; s.y += v.y; s.z += v.z; s.w += v.w;
    }
    float4 r;
    r.x = gelu_exact(s.x); r.y = gelu_exact(s.y);
    r.z = gelu_exact(s.z); r.w = gelu_exact(s.w);
    ((float4*)h2)[(size_t)row * 96 + c4] = r;
}

// ---------------- Kernel 2f: mlp2 partial GEMM, split-K=2 ----------------
// grid (512 rows, 2 kc[192]), 192 threads.
__global__ __launch_bounds__(192) void mlp2A_kernel(const float* __restrict__ h2,
                                                    const float* __restrict__ w2,
                                                    float* __restrict__ pm2) {
    __shared__ float xs[192];
    int tid = threadIdx.x;
    int row = blockIdx.x;
    int k0  = blockIdx.y * 192;
    if (tid < 48)
        ((float4*)xs)[tid] = *(const float4*)(h2 + (size_t)row * CC + k0 + 4 * tid);
    __syncthreads();

    float acc = 0.f;
    const float* wp = w2 + (size_t)k0 * 192 + tid;
    #pragma unroll 4
    for (int i = 0; i < 192; i += 4) {
        float w0 = wp[(size_t)(i + 0) * 192];
        float w1 = wp[(size_t)(i + 1) * 192];
        float w2v = wp[(size_t)(i + 2) * 192];
        float w3 = wp[(size_t)(i + 3) * 192];
        float4 xv = *(const float4*)&xs[i];
        acc += xv.x * w0 + xv.y * w1 + xv.z * w2v + xv.w * w3;
    }
    pm2[((size_t)blockIdx.y * 512 + row) * 192 + tid] = acc;
}

// ---------------- Kernel 2g: combine + bias + GELU + x w3 + reduce -> scores ----------------
// grid 512, 192 threads.
__global__ __launch_bounds__(192) void mlp2B_kernel(const float* __restrict__ pm2,
                                                    const float* __restrict__ b2,
                                                    const float* __restrict__ w3,
                                                    const float* __restrict__ b3,
                                                    float* __restrict__ scores) {
    int row = blockIdx.x, tid = threadIdx.x;
    float a = pm2[(size_t)row * 192 + tid]
            + pm2[((size_t)512 + row) * 192 + tid]
            + b2[tid];
    float v = gelu_exact(a) * w3[tid];
    #pragma unroll
    for (int off = 32; off; off >>= 1) v += __shfl_down(v, off);
    __shared__ float red[3];
    if ((tid & 63) == 0) red[tid >> 6] = v;
    __syncthreads();
    if (tid == 0) scores[row] = red[0] + red[1] + red[2] + b3[0];
}

// ---------------- Kernel 3: min-max norm + perturbed top-k -> indicators ----------------
__global__ __launch_bounds__(512) void topk_kernel(const float* __restrict__ scores,
                                                   const float* __restrict__ noise,
                                                   float* __restrict__ ind) {
    __shared__ float ns[TT];
    __shared__ float mnmx[2];
    __shared__ int counts[KK * TT];
    int b = blockIdx.x, tid = threadIdx.x;

    if (tid < TT) ns[tid] = scores[b * TT + tid];
    counts[tid & 511] = 0;
    __syncthreads();
    if (tid == 0) {
        float mn = ns[0], mx = ns[0];
        for (int t = 1; t < TT; ++t) { mn = fminf(mn, ns[t]); mx = fmaxf(mx, ns[t]); }
        mnmx[0] = mn; mnmx[1] = mx;
    }
    __syncthreads();
    if (tid < TT) ns[tid] = (ns[tid] - mnmx[0]) / (mnmx[1] - mnmx[0] + 1e-5f);
    __syncthreads();

    if (tid < NSAMP) {
        const float* nb = noise + ((size_t)b * NSAMP + tid) * TT;
        float p[TT];
        #pragma unroll
        for (int t = 0; t < TT; ++t) p[t] = ns[t] + nb[t] * 0.05f;
        int k = 0;
        #pragma unroll
        for (int t = 0; t < TT; ++t) {
            int rank = 0;
            #pragma unroll
            for (int u = 0; u < TT; ++u)
                rank += (p[u] > p[t] || (p[u] == p[t] && u < t)) ? 1 : 0;
            if (rank < KK) { atomicAdd(&counts[k * TT + t], 1); ++k; }
        }
    }
    __syncthreads();
    ind[b * (KK * TT) + tid] = (float)counts[tid] * (1.0f / NSAMP);
}

// ---------------- Kernel 4: weighted gather with active-frame compaction ----------------
__global__ __launch_bounds__(256) void gather_kernel(const float* __restrict__ x,
                                                     const float* __restrict__ ind,
                                                     float* __restrict__ out) {
    __shared__ float w[KK * TT];
    __shared__ int act[TT];
    __shared__ int nact_s;
    int b = blockIdx.y;
    int tid = threadIdx.x;
    w[tid] = ind[b * (KK * TT) + tid];
    w[256 + tid] = ind[b * (KK * TT) + 256 + tid];
    __syncthreads();
    if (tid == 0) {
        int n = 0;
        for (int t = 0; t < TT; ++t) {
            float s = 0.f;
            #pragma unroll
            for (int k = 0; k < KK; ++k) s += w[k * TT + t];
            if (s != 0.f) act[n++] = t;
        }
        nact_s = n;
    }
    __syncthreads();
    int nact = nact_s;

    int j4 = blockIdx.x * 256 + tid;
    if (j4 >= JV) return;

    const float4* xb = (const float4*)(x + (size_t)b * TT * FRAME);
    float4 acc[KK];
    #pragma unroll
    for (int k = 0; k < KK; ++k) acc[k] = make_float4(0.f, 0.f, 0.f, 0.f);

    for (int it = 0; it < nact; ++it) {
        int t = act[it];
        float4 v = xb[(size_t)t * JV + j4];
        #pragma unroll
        for (int k = 0; k < KK; ++k) {
            float wk = w[k * TT + t];
            acc[k].x += wk * v.x; acc[k].y += wk * v.y;
            acc[k].z += wk * v.z; acc[k].w += wk * v.w;
        }
    }
    float4* ob = (float4*)(out + (size_t)b * KK * FRAME);
    #pragma unroll
    for (int k = 0; k < KK; ++k)
        ob[(size_t)k * JV + j4] = acc[k];
}

extern "C" void kernel_launch(void* const* d_in, const int* in_sizes, int n_in,
                              void* d_out, int out_size, void* d_ws, size_t ws_size,
                              hipStream_t stream) {
    const float* x     = (const float*)d_in[0];
    const float* noise = (const float*)d_in[1];
    const float* ln_g  = (const float*)d_in[2];
    const float* ln_b  = (const float*)d_in[3];
    const float* w_in  = (const float*)d_in[4];
    const float* b_in  = (const float*)d_in[5];
    const float* w1    = (const float*)d_in[6];
    const float* b1    = (const float*)d_in[7];
    const float* w2    = (const float*)d_in[8];
    const float* b2    = (const float*)d_in[9];
    const float* w3    = (const float*)d_in[10];
    const float* b3    = (const float*)d_in[11];
    float* out = (float*)d_out;

    float* ws     = (float*)d_ws;
    float* xbar   = ws;                       // 512*768 (LayerNorm'd)
    float* h1     = xbar + 512 * DD;          // 512*768
    float* h2     = h1 + 512 * DD;            // 512*384
    float* scores = h2 + 512 * CC;            // 512
    float* ind    = scores + 512;             // 16*512
    float* G      = ind + BB * KK * TT;       // 16*384
    float* pfc    = G + BB * CC;              // 8*512*768
    float* pm1    = pfc + 8 * 512 * DD;       // 4*512*384
    float* pm2    = pm1 + 4 * 512 * CC;       // 2*512*192

    hipLaunchKernelGGL(pool_kernel, dim3(BB * TT), dim3(96, 4), 0, stream,
                       x, ln_g, ln_b, xbar);
    hipLaunchKernelGGL(fcinA_kernel, dim3(64, 3, 8), dim3(256), 0, stream,
                       xbar, w_in, pfc);
    hipLaunchKernelGGL(fcinB_kernel, dim3(384), dim3(256), 0, stream,
                       pfc, b_in, h1);
    hipLaunchKernelGGL(gpoolG_kernel, dim3(BB, 3), dim3(128), 0, stream,
                       h1, w1, G);
    hipLaunchKernelGGL(mlp1A_kernel, dim3(128, 2, 4), dim3(192), 0, stream,
                       h1, w1, pm1);
    hipLaunchKernelGGL(mlp1B_kernel, dim3(192), dim3(256), 0, stream,
                       pm1, G, b1, h2);
    hipLaunchKernelGGL(mlp2A_kernel, dim3(512, 2), dim3(192), 0, stream,
                       h2, w2, pm2);
    hipLaunchKernelGGL(mlp2B_kernel, dim3(512), dim3(192), 0, stream,
                       pm2, b2, w3, b3, scores);
    hipLaunchKernelGGL(topk_kernel, dim3(BB), dim3(512), 0, stream, scores, noise, ind);
    hipLaunchKernelGGL(gather_kernel, dim3((JV + 255) / 256, BB), dim3(256), 0, stream,
                       x, ind, out);
}